// Round 7
// baseline (76.012 us; speedup 1.0000x reference)
//
#include <hip/hip_runtime.h>
#include <hip/hip_bf16.h>

// RBF kernel matrix: out[i][j] = exp(-gamma * max(x2[i] + y2[j] - 2*x.y, 0))
//
// Round 7: WIDE tiles for DRAM write-page locality. Evidence: r2/r3/r6 (3
// different structures) all ~61 us = 4.8 TB/s effective writes vs 6.9 TB/s
// linear-fill calibration; the shared trait is 512-B-per-row write chunks.
// New: 64x512 tile per block -> 2 KB contiguous per output row per block.
//  - X panel (64 rows, hi/lo row-images) DMA-staged to 16 KB LDS (r3 path).
//  - Y read directly global->VGPR in FRAGMENT-LINEAR layout (r5 path):
//    coalesced 1-KB wave loads from L2/L3, streamed over 8 col-blocks.
//  - 3 MFMA passes (hi*hi + lo*hi + hi*lo), drop lo*lo (~1e-21 abs error).
//  - fused exp2 epilogue, float4 stores.
// Staging traffic ~ (1/64 + 1/512): 302 MB, ~= r3's 268 MB.

#define DD 64
#define BM 64
#define BN 512

typedef __attribute__((ext_vector_type(8))) short short8;
typedef __attribute__((ext_vector_type(4))) float f32x4;

#if __has_builtin(__builtin_amdgcn_exp2f)
#define EXP2(x) __builtin_amdgcn_exp2f(x)
#else
#define EXP2(x) exp2f(x)
#endif

__device__ __forceinline__ unsigned short f2bf_rne(float f) {
  unsigned u = __float_as_uint(f);
  unsigned r = u + 0x7FFFu + ((u >> 16) & 1u);
  return (unsigned short)(r >> 16);
}

// ---------------- prep: norms + hi/lo split ---------------------------------
// X -> swizzled row images (for LDS DMA); Y -> fragment-linear (for direct
// global->VGPR frag loads): frag (cb,s) holds cols cb*16+lr, k s*32+hg*8..+8
// at short8 index ((cb*2+s)*64 + hg*16 + lr).
__global__ __launch_bounds__(256)
void prep_mix(const float* __restrict__ X, const float* __restrict__ Y,
              unsigned short* __restrict__ XHg, unsigned short* __restrict__ XLg,
              short8* __restrict__ YHf, short8* __restrict__ YLf,
              float* __restrict__ xsq, float* __restrict__ ysq, int n) {
  int t = blockIdx.x * 256 + threadIdx.x;
  int row_g = t >> 3;
  int chunk = t & 7;                 // 8 consecutive k per thread
  int isX = (row_g < n);
  int r = isX ? row_g : row_g - n;
  const float* src = (isX ? X : Y) + (long)r * DD + chunk * 8;
  float4 v0 = ((const float4*)src)[0];
  float4 v1 = ((const float4*)src)[1];
  float f[8] = {v0.x, v0.y, v0.z, v0.w, v1.x, v1.y, v1.z, v1.w};

  short8 h8, l8;
  float ss = 0.f;
#pragma unroll
  for (int q = 0; q < 8; ++q) {
    unsigned short h = f2bf_rne(f[q]);
    float hv = __uint_as_float(((unsigned)h) << 16);
    h8[q] = (short)h;
    l8[q] = (short)f2bf_rne(f[q] - hv);
    ss = fmaf(f[q], f[q], ss);
  }
  if (isX) {
    int sw = (chunk * 16) ^ ((r & 7) << 4);   // 16-B aligned swizzled offset
    *(short8*)((char*)XHg + (long)r * 128 + sw) = h8;
    *(short8*)((char*)XLg + (long)r * 128 + sw) = l8;
  } else {
    int cb = r >> 4, lr = r & 15;
    int s = chunk >> 2, hg = chunk & 3;
    long o = ((long)(cb * 2 + s)) * 64 + hg * 16 + lr;
    YHf[o] = h8;
    YLf[o] = l8;
  }
  ss += __shfl_xor(ss, 1);
  ss += __shfl_xor(ss, 2);
  ss += __shfl_xor(ss, 4);
  if (chunk == 0) (isX ? xsq : ysq)[r] = ss;
}

// ---------------- main: 64x512 tile, 8 waves (2x4), Y streamed from global --
__global__ __launch_bounds__(512, 2)
void rbf_wide(const unsigned short* __restrict__ XHg, const unsigned short* __restrict__ XLg,
              const short8* __restrict__ YHf, const short8* __restrict__ YLf,
              const float* __restrict__ gptr,
              const float* __restrict__ xsq, const float* __restrict__ ysq,
              float* __restrict__ Out, int mcols) {
  __shared__ __align__(128) char lds[16384];   // [0,8K) XH, [8K,16K) XL

  const int tid = threadIdx.x;
  const int lane = tid & 63;
  const int wid = tid >> 6;          // 0..7
  const int wr = wid >> 2;           // 0..1 -> 32-row half
  const int wc = wid & 3;            // 0..3 -> 128-col quarter
  const long i0 = (long)blockIdx.y * BM;
  const long j0 = (long)blockIdx.x * BN;

  // ---- DMA-stage X panel row-images (2 x 8 KB)
  {
    const char* xh = (const char*)XHg + i0 * 128;
    const char* xl = (const char*)XLg + i0 * 128;
    int off = wid * 1024;                       // wave-uniform
    __builtin_amdgcn_global_load_lds(
        (const __attribute__((address_space(1))) void*)(xh + off + lane * 16),
        (__attribute__((address_space(3))) void*)(lds + off), 16, 0, 0);
    __builtin_amdgcn_global_load_lds(
        (const __attribute__((address_space(1))) void*)(xl + off + lane * 16),
        (__attribute__((address_space(3))) void*)(lds + 8192 + off), 16, 0, 0);
  }
  __syncthreads();

  const int lr = lane & 15;
  const int hg = lane >> 4;          // 0..3

  // ---- X fragments from LDS (held in registers across the col sweep)
  short8 xh[2][2], xl[2][2];         // [m2][kstep]
#pragma unroll
  for (int m2 = 0; m2 < 2; ++m2)
#pragma unroll
    for (int s = 0; s < 2; ++s) {
      int row = wr * 32 + m2 * 16 + lr;
      int off = (s * 64 + hg * 16) ^ ((row & 7) << 4);
      xh[m2][s] = *(const short8*)(lds + row * 128 + off);
      xl[m2][s] = *(const short8*)(lds + 8192 + row * 128 + off);
    }

  f32x4 acc[2][8];
#pragma unroll
  for (int a = 0; a < 2; ++a)
#pragma unroll
    for (int c = 0; c < 8; ++c) acc[a][c] = (f32x4){0.f, 0.f, 0.f, 0.f};

  // ---- sweep 8 col-blocks of 16; Y frags coalesced from global (L2/L3)
  const long cbb = (j0 + wc * 128) >> 4;   // absolute col-block base
#pragma unroll
  for (int cb = 0; cb < 8; ++cb) {
    long fo = (cbb + cb) * 2 * 64 + lane;
    short8 yh0 = YHf[fo], yh1 = YHf[fo + 64];
    short8 yl0 = YLf[fo], yl1 = YLf[fo + 64];
    // pass hi*hi
    acc[0][cb] = __builtin_amdgcn_mfma_f32_16x16x32_bf16(yh0, xh[0][0], acc[0][cb], 0, 0, 0);
    acc[1][cb] = __builtin_amdgcn_mfma_f32_16x16x32_bf16(yh0, xh[1][0], acc[1][cb], 0, 0, 0);
    acc[0][cb] = __builtin_amdgcn_mfma_f32_16x16x32_bf16(yh1, xh[0][1], acc[0][cb], 0, 0, 0);
    acc[1][cb] = __builtin_amdgcn_mfma_f32_16x16x32_bf16(yh1, xh[1][1], acc[1][cb], 0, 0, 0);
    // pass hi(Y)*lo(X)
    acc[0][cb] = __builtin_amdgcn_mfma_f32_16x16x32_bf16(yh0, xl[0][0], acc[0][cb], 0, 0, 0);
    acc[1][cb] = __builtin_amdgcn_mfma_f32_16x16x32_bf16(yh0, xl[1][0], acc[1][cb], 0, 0, 0);
    acc[0][cb] = __builtin_amdgcn_mfma_f32_16x16x32_bf16(yh1, xl[0][1], acc[0][cb], 0, 0, 0);
    acc[1][cb] = __builtin_amdgcn_mfma_f32_16x16x32_bf16(yh1, xl[1][1], acc[1][cb], 0, 0, 0);
    // pass lo(Y)*hi(X)
    acc[0][cb] = __builtin_amdgcn_mfma_f32_16x16x32_bf16(yl0, xh[0][0], acc[0][cb], 0, 0, 0);
    acc[1][cb] = __builtin_amdgcn_mfma_f32_16x16x32_bf16(yl0, xh[1][0], acc[1][cb], 0, 0, 0);
    acc[0][cb] = __builtin_amdgcn_mfma_f32_16x16x32_bf16(yl1, xh[0][1], acc[0][cb], 0, 0, 0);
    acc[1][cb] = __builtin_amdgcn_mfma_f32_16x16x32_bf16(yl1, xh[1][1], acc[1][cb], 0, 0, 0);
  }

  // ---- epilogue: out = 2^(min(c*x2 + c*y2 + 2|c|*xy, 0)), c = -g*log2e
  const float g = *gptr;
  const float cf = -g * 1.4426950408889634f;
  const float nc2 = -2.0f * cf;
#pragma unroll
  for (int m2 = 0; m2 < 2; ++m2) {
    long row = i0 + wr * 32 + m2 * 16 + lr;
    const float cxr = cf * xsq[row];
    float* op = Out + row * (long)mcols + j0 + wc * 128 + hg * 4;
#pragma unroll
    for (int cb = 0; cb < 8; ++cb) {
      float4 yq = *(const float4*)&ysq[j0 + wc * 128 + cb * 16 + hg * 4];
      float cy[4] = {cxr + cf * yq.x, cxr + cf * yq.y, cxr + cf * yq.z, cxr + cf * yq.w};
      float o[4];
#pragma unroll
      for (int j = 0; j < 4; ++j)
        o[j] = EXP2(fminf(fmaf(nc2, acc[m2][cb][j], cy[j]), 0.f));
      *(float4*)(op + cb * 16) = *(float4*)o;
    }
  }
}

// ---------------- fallback (proven round-2 path) ---------------------------
__global__ __launch_bounds__(256)
void prep_sq(const float* __restrict__ X, const float* __restrict__ Y,
             float* __restrict__ xsq, float* __restrict__ ysq, int n) {
  int t = blockIdx.x * 256 + threadIdx.x;
  int row = t >> 4;
  int c = t & 15;
  const float* src;
  float* dst;
  if (row < n) { src = X + (long)row * DD; dst = xsq + row; }
  else         { src = Y + (long)(row - n) * DD; dst = ysq + (row - n); }
  float4 v = ((const float4*)src)[c];
  float s = v.x * v.x + v.y * v.y + v.z * v.z + v.w * v.w;
  s += __shfl_xor(s, 1);
  s += __shfl_xor(s, 2);
  s += __shfl_xor(s, 4);
  s += __shfl_xor(s, 8);
  if (c == 0) *dst = s;
}

__global__ __launch_bounds__(256, 2)
void rbf_mfma_fb(const float* __restrict__ X, const float* __restrict__ Y,
                 const float* __restrict__ gptr,
                 const float* __restrict__ xsq, const float* __restrict__ ysq,
                 float* __restrict__ Out, int mcols) {
  __shared__ unsigned short XH[128 * DD], XL[128 * DD];
  __shared__ unsigned short YH[128 * DD], YL[128 * DD];
  const int tid = threadIdx.x;
  const long i0 = (long)blockIdx.y * 128;
  const long j0 = (long)blockIdx.x * 128;
#pragma unroll
  for (int it = 0; it < 16; ++it) {
    int e = it * 256 + tid;
    int half = e >> 11;
    int idx = e & 2047;
    int row = idx >> 4;
    int c4 = idx & 15;
    const float* src = half ? (Y + (j0 + row) * DD) : (X + (i0 + row) * DD);
    float4 v = ((const float4*)src)[c4];
    float f[4] = {v.x, v.y, v.z, v.w};
    unsigned short h[4], l[4];
#pragma unroll
    for (int q = 0; q < 4; ++q) {
      h[q] = f2bf_rne(f[q]);
      float hv = __uint_as_float(((unsigned)h[q]) << 16);
      l[q] = f2bf_rne(f[q] - hv);
    }
    int sw = (c4 * 8) ^ ((row & 7) << 4);
    unsigned short* Ht = half ? YH : XH;
    unsigned short* Lt = half ? YL : XL;
    *(ushort4*)((char*)Ht + row * 128 + sw) = make_ushort4(h[0], h[1], h[2], h[3]);
    *(ushort4*)((char*)Lt + row * 128 + sw) = make_ushort4(l[0], l[1], l[2], l[3]);
  }
  __syncthreads();
  const int lane = tid & 63;
  const int wid = tid >> 6;
  const int wr = wid >> 1, wc = wid & 1;
  const int lr = lane & 15;
  const int hg = lane >> 4;
  f32x4 acc[4][4];
#pragma unroll
  for (int a = 0; a < 4; ++a)
#pragma unroll
    for (int c = 0; c < 4; ++c) acc[a][c] = (f32x4){0.f, 0.f, 0.f, 0.f};
  const unsigned short* At[3] = {XH, XL, XH};
  const unsigned short* Bt[3] = {YH, YH, YL};
#pragma unroll
  for (int p = 0; p < 3; ++p) {
#pragma unroll
    for (int s = 0; s < 2; ++s) {
      const int kbyte = s * 64 + hg * 16;
      short8 af[4], bfv[4];
#pragma unroll
      for (int m2 = 0; m2 < 4; ++m2) {
        int row = wr * 64 + m2 * 16 + lr;
        af[m2] = *(const short8*)((const char*)At[p] + row * 128 + (kbyte ^ ((row & 7) << 4)));
      }
#pragma unroll
      for (int n2 = 0; n2 < 4; ++n2) {
        int row = wc * 64 + n2 * 16 + lr;
        bfv[n2] = *(const short8*)((const char*)Bt[p] + row * 128 + (kbyte ^ ((row & 7) << 4)));
      }
#pragma unroll
      for (int m2 = 0; m2 < 4; ++m2)
#pragma unroll
        for (int n2 = 0; n2 < 4; ++n2)
          acc[m2][n2] = __builtin_amdgcn_mfma_f32_16x16x32_bf16(af[m2], bfv[n2], acc[m2][n2], 0, 0, 0);
    }
  }
  const float g = *gptr;
  float yv[4];
#pragma unroll
  for (int n2 = 0; n2 < 4; ++n2) yv[n2] = ysq[j0 + wc * 64 + n2 * 16 + lr];
#pragma unroll
  for (int m2 = 0; m2 < 4; ++m2) {
#pragma unroll
    for (int j = 0; j < 4; ++j) {
      long row = i0 + wr * 64 + m2 * 16 + hg * 4 + j;
      float xr = xsq[row];
      float* op = Out + row * (long)mcols + j0 + wc * 64 + lr;
#pragma unroll
      for (int n2 = 0; n2 < 4; ++n2) {
        float d = fmaxf(xr + yv[n2] - 2.0f * acc[m2][n2][j], 0.f);
        op[n2 * 16] = __expf(-g * d);
      }
    }
  }
}

extern "C" void kernel_launch(void* const* d_in, const int* in_sizes, int n_in,
                              void* d_out, int out_size, void* d_ws, size_t ws_size,
                              hipStream_t stream) {
  const float* x = (const float*)d_in[0];
  const float* y = (const float*)d_in[1];
  const float* g = (const float*)d_in[2];
  float* out = (float*)d_out;

  const int n = in_sizes[0] / DD;   // 8192
  const int m = in_sizes[1] / DD;   // 8192

  const size_t split_bytes = (size_t)(n + m) * DD * 2 * sizeof(unsigned short);
  const size_t needed = split_bytes + (size_t)(n + m) * sizeof(float);

  if (ws_size >= needed && (n % BM) == 0 && (m % BN) == 0) {
    unsigned short* XHg = (unsigned short*)d_ws;
    unsigned short* XLg = XHg + (size_t)n * DD;
    short8* YHf = (short8*)(XLg + (size_t)n * DD);
    short8* YLf = YHf + (size_t)m * DD / 8;
    float* xsq = (float*)(YLf + (size_t)m * DD / 8);
    float* ysq = xsq + n;
    prep_mix<<<(n + m) * 8 / 256, 256, 0, stream>>>(x, y, XHg, XLg, YHf, YLf, xsq, ysq, n);
    dim3 grid(m / BN, n / BM);      // 16 x 128 = 2048 blocks
    rbf_wide<<<grid, 512, 0, stream>>>(XHg, XLg, YHf, YLf, g, xsq, ysq, out, m);
  } else {
    float* xsq = (float*)d_ws;
    float* ysq = xsq + n;
    prep_sq<<<(n + m) / 16, 256, 0, stream>>>(x, y, xsq, ysq, n);
    dim3 grid(m / 128, n / 128);
    rbf_mfma_fb<<<grid, 256, 0, stream>>>(x, y, g, xsq, ysq, out, m);
  }
}

// Round 8
// 64.501 us; speedup vs baseline: 1.1785x; 1.1785x over previous
//
#include <hip/hip_runtime.h>
#include <hip/hip_bf16.h>

// RBF kernel matrix: out[i][j] = exp(-gamma * max(x2[i] + y2[j] - 2*x.y, 0))
//
// Round 8: r6 structure + XCD-BANDED block swizzle (the only change).
// Theory: output DRAM page (~2KB) = 4 adjacent 128-col tile chunks, written
// by 4 consecutive bids -> HW round-robin puts them on 4 DIFFERENT XCDs ->
// uncorrelated L2 evictions, no page coalescing (4.8 vs 6.9 TB/s fill BW).
// Fix: xcd = bid&7 owns a contiguous 1024-col band; local bids sweep
// j-fastest. All writers of a page are co-resident on one XCD; per-XCD L2
// footprint ~4MB (= L2 size); Y band (512KB) L2-hot all kernel.
// 3 MFMA passes (hi*hi + lo*hi + hi*lo), drop lo*lo (~1e-21 abs out error).

#define DD 64
#define BM 128
#define BN 128

typedef __attribute__((ext_vector_type(8))) short short8;
typedef __attribute__((ext_vector_type(4))) float f32x4;

#if __has_builtin(__builtin_amdgcn_exp2f)
#define EXP2(x) __builtin_amdgcn_exp2f(x)
#else
#define EXP2(x) exp2f(x)
#endif

__device__ __forceinline__ unsigned short f2bf_rne(float f) {
  unsigned u = __float_as_uint(f);
  unsigned r = u + 0x7FFFu + ((u >> 16) & 1u);
  return (unsigned short)(r >> 16);
}

// ---------------- prep: fp32 norms + bf16 hi/lo pre-split (pre-swizzled) ----
__global__ __launch_bounds__(256)
void prep_split(const float* __restrict__ X, const float* __restrict__ Y,
                unsigned short* __restrict__ XHg, unsigned short* __restrict__ XLg,
                unsigned short* __restrict__ YHg, unsigned short* __restrict__ YLg,
                float* __restrict__ xsq, float* __restrict__ ysq, int n) {
  int t = blockIdx.x * 256 + threadIdx.x;
  int row = t >> 4;       // 16 lanes per row
  int c4 = t & 15;        // float4 index within row
  const float* src;
  unsigned short *hd, *ld;
  float* nd;
  int r;
  if (row < n) { r = row;     src = X + (long)r * DD; hd = XHg; ld = XLg; nd = xsq + r; }
  else         { r = row - n; src = Y + (long)r * DD; hd = YHg; ld = YLg; nd = ysq + r; }
  float4 v = ((const float4*)src)[c4];
  float f[4] = {v.x, v.y, v.z, v.w};
  unsigned short h[4], l[4];
#pragma unroll
  for (int q = 0; q < 4; ++q) {
    h[q] = f2bf_rne(f[q]);
    float hv = __uint_as_float(((unsigned)h[q]) << 16);
    l[q] = f2bf_rne(f[q] - hv);
  }
  int sw = (c4 * 8) ^ ((r & 7) << 4);   // swizzled byte offset within 128-B row
  *(ushort4*)((char*)hd + (long)r * 128 + sw) = make_ushort4(h[0], h[1], h[2], h[3]);
  *(ushort4*)((char*)ld + (long)r * 128 + sw) = make_ushort4(l[0], l[1], l[2], l[3]);
  float s = v.x * v.x + v.y * v.y + v.z * v.z + v.w * v.w;
  s += __shfl_xor(s, 1);
  s += __shfl_xor(s, 2);
  s += __shfl_xor(s, 4);
  s += __shfl_xor(s, 8);
  if (c4 == 0) *nd = s;
}

// ---------------- main: DMA-staged MFMA GEMM, 8 waves, XCD-banded swizzle ---
__global__ __launch_bounds__(512, 4)
void rbf_xcd(const unsigned short* __restrict__ XHg, const unsigned short* __restrict__ XLg,
             const unsigned short* __restrict__ YHg, const unsigned short* __restrict__ YLg,
             const float* __restrict__ gptr,
             const float* __restrict__ xsq, const float* __restrict__ ysq,
             float* __restrict__ Out, int mcols, int jper) {
  // 4 tiles of 128 rows x 128 B (swizzled image), 16 KB each = 64 KB.
  __shared__ __align__(128) char lds[65536];

  const int tid = threadIdx.x;
  const int lane = tid & 63;
  const int wid = tid >> 6;        // 0..7

  // XCD-banded mapping: xcd owns j-tiles [xcd*jper, (xcd+1)*jper);
  // within an XCD, local bids sweep j fastest (page writers co-resident).
  const int bid = blockIdx.x;
  const int xcd = bid & 7;
  const int local = bid >> 3;
  const int jj = local % jper;
  const int ii = local / jper;
  const long i0 = (long)ii * BM;
  const long j0 = (long)(xcd * jper + jj) * BN;

  // ---- stage: 4 contiguous 16-KB slices, global_load_lds width 16
  const char* srcs[4] = {(const char*)XHg + i0 * 128, (const char*)XLg + i0 * 128,
                         (const char*)YHg + j0 * 128, (const char*)YLg + j0 * 128};
#pragma unroll
  for (int t4 = 0; t4 < 4; ++t4) {
#pragma unroll
    for (int it = 0; it < 2; ++it) {
      int off = it * 8192 + wid * 1024;           // wave-uniform
      const char* g = srcs[t4] + off + lane * 16; // per-lane global src
      __builtin_amdgcn_global_load_lds(
          (const __attribute__((address_space(1))) void*)g,
          (__attribute__((address_space(3))) void*)(lds + t4 * 16384 + off),
          16, 0, 0);
    }
  }
  __syncthreads();   // compiler drains vmcnt before the barrier

  // ---- MFMA: 3 passes (hi*hi, lo*hi, hi*lo), 2 k-steps of 32 each
  const int wr = wid >> 2;         // 0..1 -> row half (64 rows)
  const int wc = wid & 3;          // 0..3 -> col quarter (32 cols)
  const int lr = lane & 15;
  const int hg = lane >> 4;        // 0..3

  f32x4 acc[4][2];
#pragma unroll
  for (int a = 0; a < 4; ++a)
#pragma unroll
    for (int b = 0; b < 2; ++b) acc[a][b] = (f32x4){0.f, 0.f, 0.f, 0.f};

  const char* At[3] = {lds, lds + 16384, lds};                 // XH, XL, XH
  const char* Bt[3] = {lds + 32768, lds + 32768, lds + 49152}; // YH, YH, YL
#pragma unroll
  for (int p = 0; p < 3; ++p) {
#pragma unroll
    for (int s = 0; s < 2; ++s) {
      const int kbyte = s * 64 + hg * 16;
      short8 af[4], bfv[2];
#pragma unroll
      for (int m2 = 0; m2 < 4; ++m2) {
        int row = wr * 64 + m2 * 16 + lr;
        af[m2] = *(const short8*)(At[p] + row * 128 + (kbyte ^ ((row & 7) << 4)));
      }
#pragma unroll
      for (int n2 = 0; n2 < 2; ++n2) {
        int row = wc * 32 + n2 * 16 + lr;
        bfv[n2] = *(const short8*)(Bt[p] + row * 128 + (kbyte ^ ((row & 7) << 4)));
      }
      // Swapped operands: reg dim = Y rows (output cols), lane&15 = X rows.
#pragma unroll
      for (int m2 = 0; m2 < 4; ++m2)
#pragma unroll
        for (int n2 = 0; n2 < 2; ++n2)
          acc[m2][n2] = __builtin_amdgcn_mfma_f32_16x16x32_bf16(bfv[n2], af[m2], acc[m2][n2], 0, 0, 0);
    }
  }

  // ---- epilogue: out = 2^( min( c*x2 + c*y2 + 2|c|*xy, 0 ) ), c = -g*log2e
  const float g = *gptr;
  const float cf = -g * 1.4426950408889634f;
  const float nc2 = -2.0f * cf;
  float cxr[4];
#pragma unroll
  for (int m2 = 0; m2 < 4; ++m2) cxr[m2] = cf * xsq[i0 + wr * 64 + m2 * 16 + lr];
  float4 cyv[2];
#pragma unroll
  for (int n2 = 0; n2 < 2; ++n2) {
    float4 yq = *(const float4*)&ysq[j0 + wc * 32 + n2 * 16 + hg * 4];
    cyv[n2] = make_float4(cf * yq.x, cf * yq.y, cf * yq.z, cf * yq.w);
  }
#pragma unroll
  for (int m2 = 0; m2 < 4; ++m2) {
    long row = i0 + wr * 64 + m2 * 16 + lr;
    float* op = Out + row * (long)mcols + j0 + wc * 32 + hg * 4;
#pragma unroll
    for (int n2 = 0; n2 < 2; ++n2) {
      float cy[4] = {cyv[n2].x, cyv[n2].y, cyv[n2].z, cyv[n2].w};
      float o[4];
#pragma unroll
      for (int j = 0; j < 4; ++j)
        o[j] = EXP2(fminf(fmaf(nc2, acc[m2][n2][j], cxr[m2] + cy[j]), 0.f));
      *(float4*)(op + n2 * 16) = *(float4*)o;
    }
  }
}

// ---------------- fallback (proven round-2 path) ---------------------------
__global__ __launch_bounds__(256)
void prep_sq(const float* __restrict__ X, const float* __restrict__ Y,
             float* __restrict__ xsq, float* __restrict__ ysq, int n) {
  int t = blockIdx.x * 256 + threadIdx.x;
  int row = t >> 4;
  int c = t & 15;
  const float* src;
  float* dst;
  if (row < n) { src = X + (long)row * DD; dst = xsq + row; }
  else         { src = Y + (long)(row - n) * DD; dst = ysq + (row - n); }
  float4 v = ((const float4*)src)[c];
  float s = v.x * v.x + v.y * v.y + v.z * v.z + v.w * v.w;
  s += __shfl_xor(s, 1);
  s += __shfl_xor(s, 2);
  s += __shfl_xor(s, 4);
  s += __shfl_xor(s, 8);
  if (c == 0) *dst = s;
}

__global__ __launch_bounds__(256, 2)
void rbf_mfma_fb(const float* __restrict__ X, const float* __restrict__ Y,
                 const float* __restrict__ gptr,
                 const float* __restrict__ xsq, const float* __restrict__ ysq,
                 float* __restrict__ Out, int mcols) {
  __shared__ unsigned short XH[128 * DD], XL[128 * DD];
  __shared__ unsigned short YH[128 * DD], YL[128 * DD];
  const int tid = threadIdx.x;
  const long i0 = (long)blockIdx.y * 128;
  const long j0 = (long)blockIdx.x * 128;
#pragma unroll
  for (int it = 0; it < 16; ++it) {
    int e = it * 256 + tid;
    int half = e >> 11;
    int idx = e & 2047;
    int row = idx >> 4;
    int c4 = idx & 15;
    const float* src = half ? (Y + (j0 + row) * DD) : (X + (i0 + row) * DD);
    float4 v = ((const float4*)src)[c4];
    float f[4] = {v.x, v.y, v.z, v.w};
    unsigned short h[4], l[4];
#pragma unroll
    for (int q = 0; q < 4; ++q) {
      h[q] = f2bf_rne(f[q]);
      float hv = __uint_as_float(((unsigned)h[q]) << 16);
      l[q] = f2bf_rne(f[q] - hv);
    }
    int sw = (c4 * 8) ^ ((row & 7) << 4);
    unsigned short* Ht = half ? YH : XH;
    unsigned short* Lt = half ? YL : XL;
    *(ushort4*)((char*)Ht + row * 128 + sw) = make_ushort4(h[0], h[1], h[2], h[3]);
    *(ushort4*)((char*)Lt + row * 128 + sw) = make_ushort4(l[0], l[1], l[2], l[3]);
  }
  __syncthreads();
  const int lane = tid & 63;
  const int wid = tid >> 6;
  const int wr = wid >> 1, wc = wid & 1;
  const int lr = lane & 15;
  const int hg = lane >> 4;
  f32x4 acc[4][4];
#pragma unroll
  for (int a = 0; a < 4; ++a)
#pragma unroll
    for (int c = 0; c < 4; ++c) acc[a][c] = (f32x4){0.f, 0.f, 0.f, 0.f};
  const unsigned short* At[3] = {XH, XL, XH};
  const unsigned short* Bt[3] = {YH, YH, YL};
#pragma unroll
  for (int p = 0; p < 3; ++p) {
#pragma unroll
    for (int s = 0; s < 2; ++s) {
      const int kbyte = s * 64 + hg * 16;
      short8 af[4], bfv[4];
#pragma unroll
      for (int m2 = 0; m2 < 4; ++m2) {
        int row = wr * 64 + m2 * 16 + lr;
        af[m2] = *(const short8*)((const char*)At[p] + row * 128 + (kbyte ^ ((row & 7) << 4)));
      }
#pragma unroll
      for (int n2 = 0; n2 < 4; ++n2) {
        int row = wc * 64 + n2 * 16 + lr;
        bfv[n2] = *(const short8*)((const char*)Bt[p] + row * 128 + (kbyte ^ ((row & 7) << 4)));
      }
#pragma unroll
      for (int m2 = 0; m2 < 4; ++m2)
#pragma unroll
        for (int n2 = 0; n2 < 4; ++n2)
          acc[m2][n2] = __builtin_amdgcn_mfma_f32_16x16x32_bf16(af[m2], bfv[n2], acc[m2][n2], 0, 0, 0);
    }
  }
  const float g = *gptr;
  float yv[4];
#pragma unroll
  for (int n2 = 0; n2 < 4; ++n2) yv[n2] = ysq[j0 + wc * 64 + n2 * 16 + lr];
#pragma unroll
  for (int m2 = 0; m2 < 4; ++m2) {
#pragma unroll
    for (int j = 0; j < 4; ++j) {
      long row = i0 + wr * 64 + m2 * 16 + hg * 4 + j;
      float xr = xsq[row];
      float* op = Out + row * (long)mcols + j0 + wc * 64 + lr;
#pragma unroll
      for (int n2 = 0; n2 < 4; ++n2) {
        float d = fmaxf(xr + yv[n2] - 2.0f * acc[m2][n2][j], 0.f);
        op[n2 * 16] = __expf(-g * d);
      }
    }
  }
}

extern "C" void kernel_launch(void* const* d_in, const int* in_sizes, int n_in,
                              void* d_out, int out_size, void* d_ws, size_t ws_size,
                              hipStream_t stream) {
  const float* x = (const float*)d_in[0];
  const float* y = (const float*)d_in[1];
  const float* g = (const float*)d_in[2];
  float* out = (float*)d_out;

  const int n = in_sizes[0] / DD;   // 8192
  const int m = in_sizes[1] / DD;   // 8192

  const size_t split_bytes = (size_t)(n + m) * DD * 2 * sizeof(unsigned short);
  const size_t needed = split_bytes + (size_t)(n + m) * sizeof(float);

  const int nit = n / BM;           // 64
  const int njt = m / BN;           // 64

  if (ws_size >= needed && (n % BM) == 0 && (m % BN) == 0 && (njt % 8) == 0) {
    unsigned short* XHg = (unsigned short*)d_ws;
    unsigned short* XLg = XHg + (size_t)n * DD;
    unsigned short* YHg = XLg + (size_t)n * DD;
    unsigned short* YLg = YHg + (size_t)m * DD;
    float* xsq = (float*)(YLg + (size_t)m * DD);
    float* ysq = xsq + n;
    prep_split<<<(n + m) / 16, 256, 0, stream>>>(x, y, XHg, XLg, YHg, YLg, xsq, ysq, n);
    const int jper = njt / 8;       // j-tiles per XCD band (8)
    rbf_xcd<<<nit * njt, 512, 0, stream>>>(XHg, XLg, YHg, YLg, g, xsq, ysq, out, m, jper);
  } else {
    float* xsq = (float*)d_ws;
    float* ysq = xsq + n;
    prep_sq<<<(n + m) / 16, 256, 0, stream>>>(x, y, xsq, ysq, n);
    dim3 grid(m / 128, n / 128);
    rbf_mfma_fb<<<grid, 256, 0, stream>>>(x, y, g, xsq, ysq, out, m);
  }
}